// Round 5
// baseline (950.048 us; speedup 1.0000x reference)
//
#include <hip/hip_runtime.h>
#include <hip/hip_bf16.h>
#include <cstddef>

constexpr int   kN  = 1024;
constexpr int   kE  = 16384;
constexpr int   kQ  = 8192;
constexpr int   kH  = 32;
constexpr size_t kNN = (size_t)kN * kN;
constexpr float kEPS = 1e-5f;
constexpr int   kStatsBlocks = 2 * kN;   // one i-row x half-k per block

using short8 = __attribute__((ext_vector_type(8))) short;
using f32x4  = __attribute__((ext_vector_type(4))) float;

// ---------------- small graph kernels ----------------

__global__ void k_edge(const int* __restrict__ ei, float* __restrict__ deg,
                       unsigned char* __restrict__ adj, unsigned char* __restrict__ adjT) {
    int e = blockIdx.x * 256 + threadIdx.x;
    if (e < kE) {
        int s = ei[e], d = ei[kE + e];
        atomicAdd(&deg[d], 1.0f);
        adj [s * kN + d] = 1;   // eim[s][d]
        adjT[d * kN + s] = 1;   // eim^T
    }
}

__global__ void k_dinv(const float* __restrict__ deg, float* __restrict__ dinv) {
    int n = blockIdx.x * 256 + threadIdx.x;
    if (n < kN) dinv[n] = rsqrtf(deg[n] + 1.0f);
}

__global__ void k_embed(const int* __restrict__ xids, const float* __restrict__ emb,
                        float* __restrict__ x0) {
    int t = blockIdx.x * 256 + threadIdx.x;  // kN*kH threads
    int n = t >> 5, c = t & 31;
    x0[t] = emb[xids[n] * kH + c];
}

// h = x @ W   (kN x 32) @ (32 x 32)
__global__ void k_node_mm(const float* __restrict__ x, const float* __restrict__ W,
                          float* __restrict__ h) {
    __shared__ float Ws[kH * kH];
    int t = threadIdx.x;
    for (int u = t; u < kH * kH; u += 256) Ws[u] = W[u];
    __syncthreads();
    int g = blockIdx.x * 256 + t;
    int n = g >> 5, c = g & 31;
    float acc = 0.f;
#pragma unroll
    for (int d = 0; d < kH; d++) acc = fmaf(x[n * kH + d], Ws[d * kH + c], acc);
    h[g] = acc;
}

__global__ void k_scatter(const int* __restrict__ ei, const float* __restrict__ h,
                          const float* __restrict__ dinv, float* __restrict__ agg) {
    int t = blockIdx.x * 256 + threadIdx.x;  // kE*kH threads
    int e = t >> 5, c = t & 31;
    int s = ei[e], d = ei[kE + e];
    atomicAdd(&agg[d * kH + c], h[s * kH + c] * dinv[s] * dinv[d]);
}

__global__ void k_gcn_post(float* __restrict__ agg, const float* __restrict__ h,
                           const float* __restrict__ dinv, const float* __restrict__ b) {
    int t = blockIdx.x * 256 + threadIdx.x;  // kN*kH
    int n = t >> 5, c = t & 31;
    agg[t] += h[t] * dinv[n] * dinv[n] + b[c];
}

// graphnorm over nodes (per channel), then relu. One block per channel.
__global__ void k_graphnorm(const float* __restrict__ x, float* __restrict__ out,
                            const float* __restrict__ g, const float* __restrict__ b,
                            const float* __restrict__ a, int M) {
    int c = blockIdx.x, t = threadIdx.x;
    float s = 0.f, ss = 0.f;
    for (int m = t; m < M; m += 256) { float v = x[m * kH + c]; s += v; ss += v * v; }
    __shared__ float rs[256], rss[256];
    rs[t] = s; rss[t] = ss;
    __syncthreads();
    for (int o = 128; o > 0; o >>= 1) {
        if (t < o) { rs[t] += rs[t + o]; rss[t] += rss[t + o]; }
        __syncthreads();
    }
    __shared__ float scale, shift;
    if (t == 0) {
        float mu  = rs[0] / (float)M;
        float ac  = a[c];
        float var = rss[0] / (float)M - 2.f * ac * mu * mu + ac * ac * mu * mu;
        float sc  = g[c] * rsqrtf(var + kEPS);
        scale = sc;
        shift = b[c] - sc * ac * mu;
    }
    __syncthreads();
    for (int m = t; m < M; m += 256) {
        float v = scale * x[m * kH + c] + shift;
        out[m * kH + c] = v > 0.f ? v : 0.f;
    }
}

// ---------------- fused x1 / x2^T generation (bf16, channel-major) ----------------
// CW=8 pinned: CW=32 fully-unrolled dual-accumulator loop spilled (R4 regression).

template<int CW>
__global__ __launch_bounds__(256) void k_genx2(
        const float* __restrict__ xn,
        const unsigned char* __restrict__ adj, const unsigned char* __restrict__ adjT,
        const float* __restrict__ w1, const float* __restrict__ b1,
        const float* __restrict__ w2, const float* __restrict__ b2,
        __hip_bfloat16* __restrict__ X1, __hip_bfloat16* __restrict__ X2t, int c0) {
    __shared__ float W1s[33 * CW], W2s[33 * CW], b1s[CW], b2s[CW], xo[kH];
    __shared__ float xis[256][kH + 1];
    int o = blockIdx.y, i0 = blockIdx.x * 256, t = threadIdx.x;
    for (int u = t; u < 33 * CW; u += 256) {
        int d = u / CW, cc = u % CW;
        W1s[u] = w1[d * kH + c0 + cc];
        W2s[u] = w2[d * kH + c0 + cc];
    }
    if (t < CW) { b1s[t] = b1[c0 + t]; b2s[t] = b2[c0 + t]; }
    if (t < kH) xo[t] = xn[o * kH + t];
    for (int u = t; u < 256 * kH; u += 256) {
        xis[u >> 5][u & 31] = xn[(i0 + (u >> 5)) * kH + (u & 31)];
    }
    __syncthreads();
    int in = i0 + t;
    float p[kH];
#pragma unroll
    for (int d = 0; d < kH; d++) p[d] = xo[d] * xis[t][d];
    float e1 = (float)adj [o * kN + in];
    float e2 = (float)adjT[o * kN + in];
#pragma unroll
    for (int cc = 0; cc < CW; cc++) {
        float v1 = b1s[cc], v2 = b2s[cc];
#pragma unroll
        for (int d = 0; d < kH; d++) {
            v1 = fmaf(p[d], W1s[d * CW + cc], v1);
            v2 = fmaf(p[d], W2s[d * CW + cc], v2);
        }
        v1 = fmaf(e1, W1s[32 * CW + cc], v1);
        v2 = fmaf(e2, W2s[32 * CW + cc], v2);
        X1 [(size_t)cc * kNN + (size_t)o * kN + in] = __float2bfloat16(v1 > 0.f ? v1 : 0.f);
        X2t[(size_t)cc * kNN + (size_t)o * kN + in] = __float2bfloat16(v2 > 0.f ? v2 : 0.f);
    }
}

// ---------------- bf16 MFMA batched GEMM: C[c] = A[c] @ B[c], B given transposed ----------------

__device__ __forceinline__ void g2l16(const unsigned short* g, unsigned short* l) {
    __builtin_amdgcn_global_load_lds(
        (const __attribute__((address_space(1))) void*)g,
        (__attribute__((address_space(3))) void*)l, 16, 0, 0);
}

__global__ __launch_bounds__(256) void k_bgemm_bf16(
        const unsigned short* __restrict__ A_, const unsigned short* __restrict__ Bt_,
        float* __restrict__ C_) {
    int c = blockIdx.z;
    const unsigned short* A  = A_  + (size_t)c * kNN;
    const unsigned short* Bt = Bt_ + (size_t)c * kNN;
    float* C = C_ + (size_t)c * kNN;
    int i0 = blockIdx.y * 128, j0 = blockIdx.x * 128;
    __shared__ unsigned short As[128 * 32];
    __shared__ unsigned short Bs[128 * 32];
    int t = threadIdx.x;
    int lane = t & 63, w = t >> 6;
    int wr = (w >> 1) * 64, wc = (w & 1) * 64;
    int l15 = lane & 15, lhi = lane >> 4;  // 0..3
    int srow = t >> 2, skel = (t & 3) * 8;
    f32x4 acc[4][4] = {};
    for (int k0 = 0; k0 < kN; k0 += 32) {
        g2l16(A  + (size_t)(i0 + srow)      * kN + k0 + skel, As + (size_t)t * 8);
        g2l16(A  + (size_t)(i0 + srow + 64) * kN + k0 + skel, As + (size_t)(t + 256) * 8);
        g2l16(Bt + (size_t)(j0 + srow)      * kN + k0 + skel, Bs + (size_t)t * 8);
        g2l16(Bt + (size_t)(j0 + srow + 64) * kN + k0 + skel, Bs + (size_t)(t + 256) * 8);
        asm volatile("s_waitcnt vmcnt(0)" ::: "memory");
        __syncthreads();
        short8 af[4], bf[4];
#pragma unroll
        for (int m = 0; m < 4; m++)
            af[m] = *(const short8*)&As[(wr + m * 16 + l15) * 32 + lhi * 8];
#pragma unroll
        for (int n = 0; n < 4; n++)
            bf[n] = *(const short8*)&Bs[(wc + n * 16 + l15) * 32 + lhi * 8];
#pragma unroll
        for (int m = 0; m < 4; m++)
#pragma unroll
            for (int n = 0; n < 4; n++)
                acc[m][n] = __builtin_amdgcn_mfma_f32_16x16x32_bf16(af[m], bf[n], acc[m][n], 0, 0, 0);
        __syncthreads();
    }
#pragma unroll
    for (int m = 0; m < 4; m++) {
        int row = i0 + wr + m * 16 + lhi * 4;
#pragma unroll
        for (int n = 0; n < 4; n++) {
            int col = j0 + wc + n * 16 + l15;
#pragma unroll
            for (int r = 0; r < 4; r++)
                C[(size_t)(row + r) * kN + col] = acc[m][n][r];
        }
    }
}

// ---------------- gn3 statistics ----------------
// 2048 blocks: block = (i-row, k-half). 2 pairs/thread in registers; per-block
// partials written to spart[block][64] (deterministic, no global atomics).

__global__ __launch_bounds__(256) void k_stats(
        const float* __restrict__ xn, const unsigned char* __restrict__ adj,
        const float* __restrict__ prod, const float* __restrict__ w3,
        const float* __restrict__ b3, float* __restrict__ spart) {
    __shared__ float W3T[kH * 68];
    __shared__ float b3s[kH], xi[kH];
    __shared__ float lsum[kH], lssq[kH];
    int t = threadIdx.x;
    for (int u = t; u < 65 * kH; u += 256) {
        int d = u >> 5, c = u & 31;                 // w3 row-major [65][32]
        int slot = d < 33 ? d : d + 3;
        W3T[c * 68 + slot] = w3[u];
    }
    int bx = blockIdx.x;
    int i = bx >> 1, kh = bx & 1;
    if (t < kH) { b3s[t] = b3[t]; lsum[t] = 0.f; lssq[t] = 0.f; }
    else if (t < 2 * kH) xi[t - kH] = xn[i * kH + (t - kH)];
    __syncthreads();
    float s[kH] = {}, q2[kH] = {};
    for (int k4 = 0; k4 < 2; k4++) {
        int k = kh * 512 + k4 * 256 + t;
        float p[kH];
#pragma unroll
        for (int q = 0; q < 8; q++) {
            float4 v = *(const float4*)&xn[k * kH + 4 * q];
            p[4 * q + 0] = xi[4 * q + 0] * v.x;
            p[4 * q + 1] = xi[4 * q + 1] * v.y;
            p[4 * q + 2] = xi[4 * q + 2] * v.z;
            p[4 * q + 3] = xi[4 * q + 3] * v.w;
        }
        float e = (float)adj[i * kN + k];
        float pr[kH];
#pragma unroll
        for (int d = 0; d < kH; d++) pr[d] = prod[(size_t)d * kNN + (size_t)i * kN + k];
#pragma unroll 4
        for (int c = 0; c < kH; c++) {
            const float* wc = &W3T[c * 68];
            float v = b3s[c];
#pragma unroll
            for (int q = 0; q < 8; q++) {
                float4 w4 = *(const float4*)(wc + 4 * q);
                v = fmaf(p[4 * q + 0], w4.x, v); v = fmaf(p[4 * q + 1], w4.y, v);
                v = fmaf(p[4 * q + 2], w4.z, v); v = fmaf(p[4 * q + 3], w4.w, v);
            }
            v = fmaf(e, wc[32], v);
#pragma unroll
            for (int q = 0; q < 8; q++) {
                float4 w4 = *(const float4*)(wc + 36 + 4 * q);
                v = fmaf(pr[4 * q + 0], w4.x, v); v = fmaf(pr[4 * q + 1], w4.y, v);
                v = fmaf(pr[4 * q + 2], w4.z, v); v = fmaf(pr[4 * q + 3], w4.w, v);
            }
            s[c] += v;
            q2[c] = fmaf(v, v, q2[c]);
        }
    }
    // 64-lane butterfly once per channel, then LDS partials, then one global write
#pragma unroll 4
    for (int c = 0; c < kH; c++) {
        float a = s[c], b = q2[c];
#pragma unroll
        for (int o = 32; o > 0; o >>= 1) { a += __shfl_xor(a, o); b += __shfl_xor(b, o); }
        if ((t & 63) == 0) { atomicAdd(&lsum[c], a); atomicAdd(&lssq[c], b); }
    }
    __syncthreads();
    if (t < kH)          spart[(size_t)bx * 64 + t]      = lsum[t];
    else if (t < 2 * kH) spart[(size_t)bx * 64 + 32 + (t - kH)] = lssq[t - kH];
}

// reduce spart[2048][64] -> scale/shift per channel
__global__ void k_finalize(const float* __restrict__ spart, const float* __restrict__ g,
                           const float* __restrict__ b, const float* __restrict__ a,
                           float* __restrict__ ss) {
    int t = threadIdx.x;  // 64 threads
    float acc = 0.f;
    for (int r = 0; r < kStatsBlocks; r++) acc += spart[(size_t)r * 64 + t];
    __shared__ float red[64];
    red[t] = acc;
    __syncthreads();
    if (t < kH) {
        float M   = (float)((double)kNN);
        float mu  = red[t] / M;
        float ac  = a[t];
        float var = red[32 + t] / M - 2.f * ac * mu * mu + ac * ac * mu * mu;
        float sc  = g[t] * rsqrtf(var + kEPS);
        ss[t]      = sc;
        ss[kH + t] = b[t] - sc * ac * mu;
    }
}

// ---------------- final: recompute y at (i,k) and (k,i), symmetrize, project ----------------

__global__ __launch_bounds__(256) void k_out(
        const int* __restrict__ pos, const float* __restrict__ xn,
        const unsigned char* __restrict__ adj, const float* __restrict__ prod,
        const float* __restrict__ w3, const float* __restrict__ b3,
        const float* __restrict__ ss, const float* __restrict__ wdir,
        const float* __restrict__ bdir, float* __restrict__ out) {
    __shared__ float W3s[65 * kH], b3s[kH], scs[kH], shs[kH], wd[kH];
    int t = threadIdx.x;
    for (int u = t; u < 65 * kH; u += 256) W3s[u] = w3[u];
    if (t < kH) { b3s[t] = b3[t]; scs[t] = ss[t]; shs[t] = ss[kH + t]; wd[t] = wdir[t]; }
    __syncthreads();
    int q = blockIdx.x * 256 + t;
    int i = pos[2 * q], k = pos[2 * q + 1];
    float p[kH], pr1[kH], pr2[kH];
#pragma unroll
    for (int d = 0; d < kH; d++) p[d] = xn[i * kH + d] * xn[k * kH + d];
#pragma unroll
    for (int d = 0; d < kH; d++) {
        pr1[d] = prod[(size_t)d * kNN + (size_t)i * kN + k];
        pr2[d] = prod[(size_t)d * kNN + (size_t)k * kN + i];
    }
    float e1 = (float)adj[i * kN + k], e2 = (float)adj[k * kN + i];
    float acc = bdir[0];
    for (int c = 0; c < kH; c++) {
        float y1 = b3s[c], y2 = b3s[c];
#pragma unroll
        for (int d = 0; d < kH; d++) {
            float w = W3s[d * kH + c];
            y1 = fmaf(p[d], w, y1); y2 = fmaf(p[d], w, y2);
        }
        y1 = fmaf(e1, W3s[32 * kH + c], y1);
        y2 = fmaf(e2, W3s[32 * kH + c], y2);
#pragma unroll
        for (int d = 0; d < kH; d++) {
            float w = W3s[(33 + d) * kH + c];
            y1 = fmaf(pr1[d], w, y1); y2 = fmaf(pr2[d], w, y2);
        }
        float z1 = scs[c] * y1 + shs[c]; z1 = z1 > 0.f ? z1 : 0.f;
        float z2 = scs[c] * y2 + shs[c]; z2 = z2 > 0.f ? z2 : 0.f;
        acc = fmaf(z1 * z2, wd[c], acc);
    }
    out[q] = acc;
}

// ---------------- launch ----------------

template<int CW>
static void run_chunks(const float* xb, const unsigned char* adj, const unsigned char* adjT,
                       const float* wm1, const float* bm1,
                       const float* wm2, const float* bm2,
                       unsigned short* X1c, unsigned short* X2c, float* prod,
                       hipStream_t stream) {
    for (int c0 = 0; c0 < kH; c0 += CW) {
        k_genx2<CW><<<dim3(4, kN), 256, 0, stream>>>(
            xb, adj, adjT, wm1, bm1, wm2, bm2,
            (__hip_bfloat16*)X1c, (__hip_bfloat16*)X2c, c0);
        k_bgemm_bf16<<<dim3(8, 8, CW), 256, 0, stream>>>(X1c, X2c, prod + (size_t)c0 * kNN);
    }
}

extern "C" void kernel_launch(void* const* d_in, const int* in_sizes, int n_in,
                              void* d_out, int out_size, void* d_ws, size_t ws_size,
                              hipStream_t stream) {
    const int*   x_ids = (const int*)d_in[0];
    const int*   ei    = (const int*)d_in[1];
    const int*   pos   = (const int*)d_in[2];
    const float* emb   = (const float*)d_in[3];
    const float* gw0   = (const float*)d_in[4];
    const float* gb0   = (const float*)d_in[5];
    const float* g0g   = (const float*)d_in[6];
    const float* g0b   = (const float*)d_in[7];
    const float* g0a   = (const float*)d_in[8];
    const float* gw1   = (const float*)d_in[9];
    const float* gb1   = (const float*)d_in[10];
    const float* g1g   = (const float*)d_in[11];
    const float* g1b   = (const float*)d_in[12];
    const float* g1a   = (const float*)d_in[13];
    const float* wm1   = (const float*)d_in[14];
    const float* bm1   = (const float*)d_in[15];
    const float* wm2   = (const float*)d_in[16];
    const float* bm2   = (const float*)d_in[17];
    const float* wm3   = (const float*)d_in[18];
    const float* bm3   = (const float*)d_in[19];
    const float* g3g   = (const float*)d_in[20];
    const float* g3b   = (const float*)d_in[21];
    const float* g3a   = (const float*)d_in[22];
    const float* wdir  = (const float*)d_in[23];
    const float* bdir  = (const float*)d_in[24];
    float* out = (float*)d_out;

    // channel-chunk width: CW=8 pinned (CW=32 spilled in genx2 — R4 regression)
    const size_t fixedF = (size_t)kH * kNN;           // prod floats
    const size_t tailB  = 2 * kNN + (2 << 20);        // adj + adjT + node bufs + spart
    int CW = 1;
    if (ws_size >= fixedF * 4 + 2 * 8 * kNN * 2 + tailB)      CW = 8;
    else if (ws_size >= fixedF * 4 + 2 * 2 * kNN * 2 + tailB) CW = 2;

    // workspace layout
    float* prod = (float*)d_ws;                                   // 128 MB
    unsigned short* X1c = (unsigned short*)(prod + fixedF);       // CW*2MB bf16
    unsigned short* X2c = X1c + (size_t)CW * kNN;                 // CW*2MB bf16 (transposed)
    unsigned char* adj  = (unsigned char*)(X2c + (size_t)CW * kNN);  // 1 MB
    unsigned char* adjT = adj + kNN;                                  // 1 MB
    float* deg   = (float*)(adjT + kNN);
    float* dinv  = deg + kN;
    float* x0    = dinv + kN;
    float* h     = x0 + kN * kH;
    float* agg   = h + kN * kH;
    float* xa    = agg + kN * kH;
    float* xb    = xa + kN * kH;
    float* spart = xb + kN * kH;                 // 2048*64 floats (512 KB)
    float* ss    = spart + (size_t)kStatsBlocks * 64;

    hipMemsetAsync(deg, 0, kN * sizeof(float), stream);
    hipMemsetAsync(adj, 0, 2 * kNN, stream);   // adj + adjT contiguous
    hipMemsetAsync(agg, 0, kN * kH * sizeof(float), stream);

    k_edge<<<(kE + 255) / 256, 256, 0, stream>>>(ei, deg, adj, adjT);
    k_dinv<<<4, 256, 0, stream>>>(deg, dinv);
    k_embed<<<kN * kH / 256, 256, 0, stream>>>(x_ids, emb, x0);

    // GCN layer 0
    k_node_mm<<<kN * kH / 256, 256, 0, stream>>>(x0, gw0, h);
    k_scatter<<<kE * kH / 256, 256, 0, stream>>>(ei, h, dinv, agg);
    k_gcn_post<<<kN * kH / 256, 256, 0, stream>>>(agg, h, dinv, gb0);
    k_graphnorm<<<kH, 256, 0, stream>>>(agg, xa, g0g, g0b, g0a, kN);

    // GCN layer 1
    hipMemsetAsync(agg, 0, kN * kH * sizeof(float), stream);
    k_node_mm<<<kN * kH / 256, 256, 0, stream>>>(xa, gw1, h);
    k_scatter<<<kE * kH / 256, 256, 0, stream>>>(ei, h, dinv, agg);
    k_gcn_post<<<kN * kH / 256, 256, 0, stream>>>(agg, h, dinv, gb1);
    k_graphnorm<<<kH, 256, 0, stream>>>(agg, xb, g1g, g1b, g1a, kN);

    // fused pairwise bf16 features + batched per-channel MFMA GEMMs, channel-chunked
    if (CW == 8)      run_chunks<8>(xb, adj, adjT, wm1, bm1, wm2, bm2, X1c, X2c, prod, stream);
    else if (CW == 2) run_chunks<2>(xb, adj, adjT, wm1, bm1, wm2, bm2, X1c, X2c, prod, stream);
    else              run_chunks<1>(xb, adj, adjT, wm1, bm1, wm2, bm2, X1c, X2c, prod, stream);

    // gn3 stats: 2048 blocks, deterministic partials + reduce
    k_stats<<<kStatsBlocks, 256, 0, stream>>>(xb, adj, prod, wm3, bm3, spart);
    k_finalize<<<1, 64, 0, stream>>>(spart, g3g, g3b, g3a, ss);

    // final gather + symmetric product + projection
    k_out<<<kQ / 256, 256, 0, stream>>>(pos, xb, adj, prod, wm3, bm3, ss, wdir, bdir, out);
}

// Round 6
// 925.518 us; speedup vs baseline: 1.0265x; 1.0265x over previous
//
#include <hip/hip_runtime.h>
#include <hip/hip_bf16.h>
#include <cstddef>

constexpr int   kN  = 1024;
constexpr int   kE  = 16384;
constexpr int   kQ  = 8192;
constexpr int   kH  = 32;
constexpr size_t kNN = (size_t)kN * kN;
constexpr float kEPS = 1e-5f;
constexpr int   kStatsBlocks = 2 * kN;   // (i-row, k-half) per block

using short8 = __attribute__((ext_vector_type(8))) short;
using f32x4  = __attribute__((ext_vector_type(4))) float;

// ---------------- small graph kernels ----------------

__global__ void k_edge(const int* __restrict__ ei, float* __restrict__ deg,
                       unsigned char* __restrict__ adj, unsigned char* __restrict__ adjT) {
    int e = blockIdx.x * 256 + threadIdx.x;
    if (e < kE) {
        int s = ei[e], d = ei[kE + e];
        atomicAdd(&deg[d], 1.0f);
        adj [s * kN + d] = 1;   // eim[s][d]
        adjT[d * kN + s] = 1;   // eim^T
    }
}

__global__ void k_dinv(const float* __restrict__ deg, float* __restrict__ dinv) {
    int n = blockIdx.x * 256 + threadIdx.x;
    if (n < kN) dinv[n] = rsqrtf(deg[n] + 1.0f);
}

__global__ void k_embed(const int* __restrict__ xids, const float* __restrict__ emb,
                        float* __restrict__ x0) {
    int t = blockIdx.x * 256 + threadIdx.x;  // kN*kH threads
    int n = t >> 5, c = t & 31;
    x0[t] = emb[xids[n] * kH + c];
}

// h = x @ W   (kN x 32) @ (32 x 32)
__global__ void k_node_mm(const float* __restrict__ x, const float* __restrict__ W,
                          float* __restrict__ h) {
    __shared__ float Ws[kH * kH];
    int t = threadIdx.x;
    for (int u = t; u < kH * kH; u += 256) Ws[u] = W[u];
    __syncthreads();
    int g = blockIdx.x * 256 + t;
    int n = g >> 5, c = g & 31;
    float acc = 0.f;
#pragma unroll
    for (int d = 0; d < kH; d++) acc = fmaf(x[n * kH + d], Ws[d * kH + c], acc);
    h[g] = acc;
}

__global__ void k_scatter(const int* __restrict__ ei, const float* __restrict__ h,
                          const float* __restrict__ dinv, float* __restrict__ agg) {
    int t = blockIdx.x * 256 + threadIdx.x;  // kE*kH threads
    int e = t >> 5, c = t & 31;
    int s = ei[e], d = ei[kE + e];
    atomicAdd(&agg[d * kH + c], h[s * kH + c] * dinv[s] * dinv[d]);
}

__global__ void k_gcn_post(float* __restrict__ agg, const float* __restrict__ h,
                           const float* __restrict__ dinv, const float* __restrict__ b) {
    int t = blockIdx.x * 256 + threadIdx.x;  // kN*kH
    int n = t >> 5, c = t & 31;
    agg[t] += h[t] * dinv[n] * dinv[n] + b[c];
}

// graphnorm over nodes (per channel), then relu. One block per channel.
__global__ void k_graphnorm(const float* __restrict__ x, float* __restrict__ out,
                            const float* __restrict__ g, const float* __restrict__ b,
                            const float* __restrict__ a, int M) {
    int c = blockIdx.x, t = threadIdx.x;
    float s = 0.f, ss = 0.f;
    for (int m = t; m < M; m += 256) { float v = x[m * kH + c]; s += v; ss += v * v; }
    __shared__ float rs[256], rss[256];
    rs[t] = s; rss[t] = ss;
    __syncthreads();
    for (int o = 128; o > 0; o >>= 1) {
        if (t < o) { rs[t] += rs[t + o]; rss[t] += rss[t + o]; }
        __syncthreads();
    }
    __shared__ float scale, shift;
    if (t == 0) {
        float mu  = rs[0] / (float)M;
        float ac  = a[c];
        float var = rss[0] / (float)M - 2.f * ac * mu * mu + ac * ac * mu * mu;
        float sc  = g[c] * rsqrtf(var + kEPS);
        scale = sc;
        shift = b[c] - sc * ac * mu;
    }
    __syncthreads();
    for (int m = t; m < M; m += 256) {
        float v = scale * x[m * kH + c] + shift;
        out[m * kH + c] = v > 0.f ? v : 0.f;
    }
}

// ---------------- fused x1 / x2^T generation (bf16, channel-major), CW=8 pinned ----------------

template<int CW>
__global__ __launch_bounds__(256) void k_genx2(
        const float* __restrict__ xn,
        const unsigned char* __restrict__ adj, const unsigned char* __restrict__ adjT,
        const float* __restrict__ w1, const float* __restrict__ b1,
        const float* __restrict__ w2, const float* __restrict__ b2,
        __hip_bfloat16* __restrict__ X1, __hip_bfloat16* __restrict__ X2t, int c0) {
    __shared__ float W1s[33 * CW], W2s[33 * CW], b1s[CW], b2s[CW], xo[kH];
    __shared__ float xis[256][kH + 1];
    int o = blockIdx.y, i0 = blockIdx.x * 256, t = threadIdx.x;
    for (int u = t; u < 33 * CW; u += 256) {
        int d = u / CW, cc = u % CW;
        W1s[u] = w1[d * kH + c0 + cc];
        W2s[u] = w2[d * kH + c0 + cc];
    }
    if (t < CW) { b1s[t] = b1[c0 + t]; b2s[t] = b2[c0 + t]; }
    if (t < kH) xo[t] = xn[o * kH + t];
    for (int u = t; u < 256 * kH; u += 256) {
        xis[u >> 5][u & 31] = xn[(i0 + (u >> 5)) * kH + (u & 31)];
    }
    __syncthreads();
    int in = i0 + t;
    float p[kH];
#pragma unroll
    for (int d = 0; d < kH; d++) p[d] = xo[d] * xis[t][d];
    float e1 = (float)adj [o * kN + in];
    float e2 = (float)adjT[o * kN + in];
#pragma unroll
    for (int cc = 0; cc < CW; cc++) {
        float v1 = b1s[cc], v2 = b2s[cc];
#pragma unroll
        for (int d = 0; d < kH; d++) {
            v1 = fmaf(p[d], W1s[d * CW + cc], v1);
            v2 = fmaf(p[d], W2s[d * CW + cc], v2);
        }
        v1 = fmaf(e1, W1s[32 * CW + cc], v1);
        v2 = fmaf(e2, W2s[32 * CW + cc], v2);
        X1 [(size_t)cc * kNN + (size_t)o * kN + in] = __float2bfloat16(v1 > 0.f ? v1 : 0.f);
        X2t[(size_t)cc * kNN + (size_t)o * kN + in] = __float2bfloat16(v2 > 0.f ? v2 : 0.f);
    }
}

// ---------------- bf16 MFMA batched GEMM: C[c] = A[c] @ B[c], B given transposed ----------------

__device__ __forceinline__ void g2l16(const unsigned short* g, unsigned short* l) {
    __builtin_amdgcn_global_load_lds(
        (const __attribute__((address_space(1))) void*)g,
        (__attribute__((address_space(3))) void*)l, 16, 0, 0);
}

__global__ __launch_bounds__(256) void k_bgemm_bf16(
        const unsigned short* __restrict__ A_, const unsigned short* __restrict__ Bt_,
        float* __restrict__ C_) {
    int c = blockIdx.z;
    const unsigned short* A  = A_  + (size_t)c * kNN;
    const unsigned short* Bt = Bt_ + (size_t)c * kNN;
    float* C = C_ + (size_t)c * kNN;
    int i0 = blockIdx.y * 128, j0 = blockIdx.x * 128;
    __shared__ unsigned short As[128 * 32];
    __shared__ unsigned short Bs[128 * 32];
    int t = threadIdx.x;
    int lane = t & 63, w = t >> 6;
    int wr = (w >> 1) * 64, wc = (w & 1) * 64;
    int l15 = lane & 15, lhi = lane >> 4;  // 0..3
    int srow = t >> 2, skel = (t & 3) * 8;
    f32x4 acc[4][4] = {};
    for (int k0 = 0; k0 < kN; k0 += 32) {
        g2l16(A  + (size_t)(i0 + srow)      * kN + k0 + skel, As + (size_t)t * 8);
        g2l16(A  + (size_t)(i0 + srow + 64) * kN + k0 + skel, As + (size_t)(t + 256) * 8);
        g2l16(Bt + (size_t)(j0 + srow)      * kN + k0 + skel, Bs + (size_t)t * 8);
        g2l16(Bt + (size_t)(j0 + srow + 64) * kN + k0 + skel, Bs + (size_t)(t + 256) * 8);
        asm volatile("s_waitcnt vmcnt(0)" ::: "memory");
        __syncthreads();
        short8 af[4], bf[4];
#pragma unroll
        for (int m = 0; m < 4; m++)
            af[m] = *(const short8*)&As[(wr + m * 16 + l15) * 32 + lhi * 8];
#pragma unroll
        for (int n = 0; n < 4; n++)
            bf[n] = *(const short8*)&Bs[(wc + n * 16 + l15) * 32 + lhi * 8];
#pragma unroll
        for (int m = 0; m < 4; m++)
#pragma unroll
            for (int n = 0; n < 4; n++)
                acc[m][n] = __builtin_amdgcn_mfma_f32_16x16x32_bf16(af[m], bf[n], acc[m][n], 0, 0, 0);
        __syncthreads();
    }
#pragma unroll
    for (int m = 0; m < 4; m++) {
        int row = i0 + wr + m * 16 + lhi * 4;
#pragma unroll
        for (int n = 0; n < 4; n++) {
            int col = j0 + wc + n * 16 + l15;
#pragma unroll
            for (int r = 0; r < 4; r++)
                C[(size_t)(row + r) * kN + col] = acc[m][n][r];
        }
    }
}

// ---------------- gn3 statistics ----------------
// 2048 blocks = (i-row, k-half). Two 256-wide k-tiles per block; P-tile staged
// to LDS with coalesced float4 row loads; pr[] read back as free ds_read_b32.
// Per-block partials to spart[block][64]; reduced by k_reduce (parallel).

__global__ __launch_bounds__(256) void k_stats(
        const float* __restrict__ xn, const unsigned char* __restrict__ adj,
        const float* __restrict__ prod, const float* __restrict__ w3,
        const float* __restrict__ b3, float* __restrict__ spart) {
    __shared__ float Pt[kH][256];        // 32 KB staged P-tile
    __shared__ float W3T[kH * 68];
    __shared__ float b3s[kH], xi[kH], lsum[kH], lssq[kH];
    int t = threadIdx.x;
    for (int u = t; u < 65 * kH; u += 256) {
        int d = u >> 5, c = u & 31;                 // w3 row-major [65][32]
        int slot = d < 33 ? d : d + 3;
        W3T[c * 68 + slot] = w3[u];
    }
    int bx = blockIdx.x;
    int i = bx >> 1, kh = bx & 1;
    if (t < kH) { b3s[t] = b3[t]; lsum[t] = 0.f; lssq[t] = 0.f; }
    else if (t < 2 * kH) xi[t - kH] = xn[i * kH + (t - kH)];
    float s[kH] = {}, q2[kH] = {};
    for (int kt = 0; kt < 2; kt++) {
        int k0 = kh * 512 + kt * 256;
        __syncthreads();   // iter0: staging done below; iter1: protect Pt reuse
        for (int u = t; u < kH * 64; u += 256) {    // 2048 float4 slots
            int d = u >> 6, c4 = (u & 63) << 2;
            *(float4*)&Pt[d][c4] =
                *(const float4*)&prod[(size_t)d * kNN + (size_t)i * kN + k0 + c4];
        }
        __syncthreads();
        int k = k0 + t;
        float p[kH];
#pragma unroll
        for (int q = 0; q < 8; q++) {
            float4 v = *(const float4*)&xn[k * kH + 4 * q];
            p[4 * q + 0] = xi[4 * q + 0] * v.x;
            p[4 * q + 1] = xi[4 * q + 1] * v.y;
            p[4 * q + 2] = xi[4 * q + 2] * v.z;
            p[4 * q + 3] = xi[4 * q + 3] * v.w;
        }
        float e = (float)adj[i * kN + k];
        float pr[kH];
#pragma unroll
        for (int d = 0; d < kH; d++) pr[d] = Pt[d][t];   // 2-way bank alias: free
#pragma unroll 4
        for (int c = 0; c < kH; c++) {
            const float* wc = &W3T[c * 68];
            float v = b3s[c];
#pragma unroll
            for (int q = 0; q < 8; q++) {
                float4 w4 = *(const float4*)(wc + 4 * q);
                v = fmaf(p[4 * q + 0], w4.x, v); v = fmaf(p[4 * q + 1], w4.y, v);
                v = fmaf(p[4 * q + 2], w4.z, v); v = fmaf(p[4 * q + 3], w4.w, v);
            }
            v = fmaf(e, wc[32], v);
#pragma unroll
            for (int q = 0; q < 8; q++) {
                float4 w4 = *(const float4*)(wc + 36 + 4 * q);
                v = fmaf(pr[4 * q + 0], w4.x, v); v = fmaf(pr[4 * q + 1], w4.y, v);
                v = fmaf(pr[4 * q + 2], w4.z, v); v = fmaf(pr[4 * q + 3], w4.w, v);
            }
            s[c] += v;
            q2[c] = fmaf(v, v, q2[c]);
        }
    }
    // 64-lane butterfly per channel, LDS partials, one global write per block
#pragma unroll 4
    for (int c = 0; c < kH; c++) {
        float a = s[c], b = q2[c];
#pragma unroll
        for (int o = 32; o > 0; o >>= 1) { a += __shfl_xor(a, o); b += __shfl_xor(b, o); }
        if ((t & 63) == 0) { atomicAdd(&lsum[c], a); atomicAdd(&lssq[c], b); }
    }
    __syncthreads();
    if (t < kH)          spart[(size_t)bx * 64 + t]             = lsum[t];
    else if (t < 2 * kH) spart[(size_t)bx * 64 + 32 + (t - kH)] = lssq[t - kH];
}

// parallel reduce spart[2048][64] -> stats[64]
__global__ __launch_bounds__(256) void k_reduce(const float* __restrict__ spart,
                                                float* __restrict__ stats) {
    int slot = blockIdx.x;   // 64 blocks
    int t = threadIdx.x;
    float acc = 0.f;
    for (int r = t; r < kStatsBlocks; r += 256) acc += spart[(size_t)r * 64 + slot];
    __shared__ float red[256];
    red[t] = acc;
    __syncthreads();
    for (int o = 128; o > 0; o >>= 1) {
        if (t < o) red[t] += red[t + o];
        __syncthreads();
    }
    if (t == 0) stats[slot] = red[0];
}

__global__ void k_finalize(const float* __restrict__ stats, const float* __restrict__ g,
                           const float* __restrict__ b, const float* __restrict__ a,
                           float* __restrict__ ss) {
    int c = threadIdx.x;  // 32 threads
    float M   = (float)((double)kNN);
    float mu  = stats[c] / M;
    float ac  = a[c];
    float var = stats[kH + c] / M - 2.f * ac * mu * mu + ac * ac * mu * mu;
    float sc  = g[c] * rsqrtf(var + kEPS);
    ss[c]      = sc;
    ss[kH + c] = b[c] - sc * ac * mu;
}

// ---------------- final: recompute y at (i,k) and (k,i), symmetrize, project ----------------

__global__ __launch_bounds__(256) void k_out(
        const int* __restrict__ pos, const float* __restrict__ xn,
        const unsigned char* __restrict__ adj, const float* __restrict__ prod,
        const float* __restrict__ w3, const float* __restrict__ b3,
        const float* __restrict__ ss, const float* __restrict__ wdir,
        const float* __restrict__ bdir, float* __restrict__ out) {
    __shared__ float W3s[65 * kH], b3s[kH], scs[kH], shs[kH], wd[kH];
    int t = threadIdx.x;
    for (int u = t; u < 65 * kH; u += 256) W3s[u] = w3[u];
    if (t < kH) { b3s[t] = b3[t]; scs[t] = ss[t]; shs[t] = ss[kH + t]; wd[t] = wdir[t]; }
    __syncthreads();
    int q = blockIdx.x * 256 + t;
    int i = pos[2 * q], k = pos[2 * q + 1];
    float p[kH], pr1[kH], pr2[kH];
#pragma unroll
    for (int d = 0; d < kH; d++) p[d] = xn[i * kH + d] * xn[k * kH + d];
#pragma unroll
    for (int d = 0; d < kH; d++) {
        pr1[d] = prod[(size_t)d * kNN + (size_t)i * kN + k];
        pr2[d] = prod[(size_t)d * kNN + (size_t)k * kN + i];
    }
    float e1 = (float)adj[i * kN + k], e2 = (float)adj[k * kN + i];
    float acc = bdir[0];
    for (int c = 0; c < kH; c++) {
        float y1 = b3s[c], y2 = b3s[c];
#pragma unroll
        for (int d = 0; d < kH; d++) {
            float w = W3s[d * kH + c];
            y1 = fmaf(p[d], w, y1); y2 = fmaf(p[d], w, y2);
        }
        y1 = fmaf(e1, W3s[32 * kH + c], y1);
        y2 = fmaf(e2, W3s[32 * kH + c], y2);
#pragma unroll
        for (int d = 0; d < kH; d++) {
            float w = W3s[(33 + d) * kH + c];
            y1 = fmaf(pr1[d], w, y1); y2 = fmaf(pr2[d], w, y2);
        }
        float z1 = scs[c] * y1 + shs[c]; z1 = z1 > 0.f ? z1 : 0.f;
        float z2 = scs[c] * y2 + shs[c]; z2 = z2 > 0.f ? z2 : 0.f;
        acc = fmaf(z1 * z2, wd[c], acc);
    }
    out[q] = acc;
}

// ---------------- launch ----------------

template<int CW>
static void run_chunks(const float* xb, const unsigned char* adj, const unsigned char* adjT,
                       const float* wm1, const float* bm1,
                       const float* wm2, const float* bm2,
                       unsigned short* X1c, unsigned short* X2c, float* prod,
                       hipStream_t stream) {
    for (int c0 = 0; c0 < kH; c0 += CW) {
        k_genx2<CW><<<dim3(4, kN), 256, 0, stream>>>(
            xb, adj, adjT, wm1, bm1, wm2, bm2,
            (__hip_bfloat16*)X1c, (__hip_bfloat16*)X2c, c0);
        k_bgemm_bf16<<<dim3(8, 8, CW), 256, 0, stream>>>(X1c, X2c, prod + (size_t)c0 * kNN);
    }
}

extern "C" void kernel_launch(void* const* d_in, const int* in_sizes, int n_in,
                              void* d_out, int out_size, void* d_ws, size_t ws_size,
                              hipStream_t stream) {
    const int*   x_ids = (const int*)d_in[0];
    const int*   ei    = (const int*)d_in[1];
    const int*   pos   = (const int*)d_in[2];
    const float* emb   = (const float*)d_in[3];
    const float* gw0   = (const float*)d_in[4];
    const float* gb0   = (const float*)d_in[5];
    const float* g0g   = (const float*)d_in[6];
    const float* g0b   = (const float*)d_in[7];
    const float* g0a   = (const float*)d_in[8];
    const float* gw1   = (const float*)d_in[9];
    const float* gb1   = (const float*)d_in[10];
    const float* g1g   = (const float*)d_in[11];
    const float* g1b   = (const float*)d_in[12];
    const float* g1a   = (const float*)d_in[13];
    const float* wm1   = (const float*)d_in[14];
    const float* bm1   = (const float*)d_in[15];
    const float* wm2   = (const float*)d_in[16];
    const float* bm2   = (const float*)d_in[17];
    const float* wm3   = (const float*)d_in[18];
    const float* bm3   = (const float*)d_in[19];
    const float* g3g   = (const float*)d_in[20];
    const float* g3b   = (const float*)d_in[21];
    const float* g3a   = (const float*)d_in[22];
    const float* wdir  = (const float*)d_in[23];
    const float* bdir  = (const float*)d_in[24];
    float* out = (float*)d_out;

    // channel-chunk width: CW=8 pinned (CW=32 spilled in genx2 — R4 regression)
    const size_t fixedF = (size_t)kH * kNN;           // prod floats
    const size_t tailB  = 2 * kNN + (2 << 20);        // adj + adjT + node bufs + spart
    int CW = 1;
    if (ws_size >= fixedF * 4 + 2 * 8 * kNN * 2 + tailB)      CW = 8;
    else if (ws_size >= fixedF * 4 + 2 * 2 * kNN * 2 + tailB) CW = 2;

    // workspace layout
    float* prod = (float*)d_ws;                                   // 128 MB
    unsigned short* X1c = (unsigned short*)(prod + fixedF);       // CW*2MB bf16
    unsigned short* X2c = X1c + (size_t)CW * kNN;                 // CW*2MB bf16 (transposed)
    unsigned char* adj  = (unsigned char*)(X2c + (size_t)CW * kNN);  // 1 MB
    unsigned char* adjT = adj + kNN;                                  // 1 MB
    float* deg   = (float*)(adjT + kNN);
    float* dinv  = deg + kN;
    float* x0    = dinv + kN;
    float* h     = x0 + kN * kH;
    float* agg   = h + kN * kH;
    float* xa    = agg + kN * kH;
    float* xb    = xa + kN * kH;
    float* spart = xb + kN * kH;                 // 2048*64 floats (512 KB)
    float* stats = spart + (size_t)kStatsBlocks * 64;
    float* ss    = stats + 2 * kH;

    hipMemsetAsync(deg, 0, kN * sizeof(float), stream);
    hipMemsetAsync(adj, 0, 2 * kNN, stream);   // adj + adjT contiguous
    hipMemsetAsync(agg, 0, kN * kH * sizeof(float), stream);

    k_edge<<<(kE + 255) / 256, 256, 0, stream>>>(ei, deg, adj, adjT);
    k_dinv<<<4, 256, 0, stream>>>(deg, dinv);
    k_embed<<<kN * kH / 256, 256, 0, stream>>>(x_ids, emb, x0);

    // GCN layer 0
    k_node_mm<<<kN * kH / 256, 256, 0, stream>>>(x0, gw0, h);
    k_scatter<<<kE * kH / 256, 256, 0, stream>>>(ei, h, dinv, agg);
    k_gcn_post<<<kN * kH / 256, 256, 0, stream>>>(agg, h, dinv, gb0);
    k_graphnorm<<<kH, 256, 0, stream>>>(agg, xa, g0g, g0b, g0a, kN);

    // GCN layer 1
    hipMemsetAsync(agg, 0, kN * kH * sizeof(float), stream);
    k_node_mm<<<kN * kH / 256, 256, 0, stream>>>(xa, gw1, h);
    k_scatter<<<kE * kH / 256, 256, 0, stream>>>(ei, h, dinv, agg);
    k_gcn_post<<<kN * kH / 256, 256, 0, stream>>>(agg, h, dinv, gb1);
    k_graphnorm<<<kH, 256, 0, stream>>>(agg, xb, g1g, g1b, g1a, kN);

    // fused pairwise bf16 features + batched per-channel MFMA GEMMs, channel-chunked
    if (CW == 8)      run_chunks<8>(xb, adj, adjT, wm1, bm1, wm2, bm2, X1c, X2c, prod, stream);
    else if (CW == 2) run_chunks<2>(xb, adj, adjT, wm1, bm1, wm2, bm2, X1c, X2c, prod, stream);
    else              run_chunks<1>(xb, adj, adjT, wm1, bm1, wm2, bm2, X1c, X2c, prod, stream);

    // gn3 stats: LDS-staged P-tiles, deterministic partials + parallel reduce
    k_stats<<<kStatsBlocks, 256, 0, stream>>>(xb, adj, prod, wm3, bm3, spart);
    k_reduce<<<64, 256, 0, stream>>>(spart, stats);
    k_finalize<<<1, 32, 0, stream>>>(stats, g3g, g3b, g3a, ss);

    // final gather + symmetric product + projection
    k_out<<<kQ / 256, 256, 0, stream>>>(pos, xb, adj, prod, wm3, bm3, ss, wdir, bdir, out);
}

// Round 7
// 664.762 us; speedup vs baseline: 1.4292x; 1.3923x over previous
//
#include <hip/hip_runtime.h>
#include <hip/hip_bf16.h>
#include <cstddef>

constexpr int   kN  = 1024;
constexpr int   kE  = 16384;
constexpr int   kQ  = 8192;
constexpr int   kH  = 32;
constexpr size_t kNN = (size_t)kN * kN;
constexpr float kEPS = 1e-5f;
constexpr int   kCW = 8;              // channel chunk width, pinned (R3-proven)
constexpr int   kStatsBlocks = kN;    // one i-row per block

using short8 = __attribute__((ext_vector_type(8))) short;
using f32x4  = __attribute__((ext_vector_type(4))) float;

// ---------------- small graph kernels ----------------

__global__ void k_edge(const int* __restrict__ ei, float* __restrict__ deg,
                       unsigned char* __restrict__ adj, unsigned char* __restrict__ adjT) {
    int e = blockIdx.x * 256 + threadIdx.x;
    if (e < kE) {
        int s = ei[e], d = ei[kE + e];
        atomicAdd(&deg[d], 1.0f);
        adj [s * kN + d] = 1;   // eim[s][d]
        adjT[d * kN + s] = 1;   // eim^T
    }
}

__global__ void k_dinv(const float* __restrict__ deg, float* __restrict__ dinv) {
    int n = blockIdx.x * 256 + threadIdx.x;
    if (n < kN) dinv[n] = rsqrtf(deg[n] + 1.0f);
}

__global__ void k_embed(const int* __restrict__ xids, const float* __restrict__ emb,
                        float* __restrict__ x0) {
    int t = blockIdx.x * 256 + threadIdx.x;  // kN*kH threads
    int n = t >> 5, c = t & 31;
    x0[t] = emb[xids[n] * kH + c];
}

// h = x @ W   (kN x 32) @ (32 x 32)
__global__ void k_node_mm(const float* __restrict__ x, const float* __restrict__ W,
                          float* __restrict__ h) {
    __shared__ float Ws[kH * kH];
    int t = threadIdx.x;
    for (int u = t; u < kH * kH; u += 256) Ws[u] = W[u];
    __syncthreads();
    int g = blockIdx.x * 256 + t;
    int n = g >> 5, c = g & 31;
    float acc = 0.f;
#pragma unroll
    for (int d = 0; d < kH; d++) acc = fmaf(x[n * kH + d], Ws[d * kH + c], acc);
    h[g] = acc;
}

__global__ void k_scatter(const int* __restrict__ ei, const float* __restrict__ h,
                          const float* __restrict__ dinv, float* __restrict__ agg) {
    int t = blockIdx.x * 256 + threadIdx.x;  // kE*kH threads
    int e = t >> 5, c = t & 31;
    int s = ei[e], d = ei[kE + e];
    atomicAdd(&agg[d * kH + c], h[s * kH + c] * dinv[s] * dinv[d]);
}

__global__ void k_gcn_post(float* __restrict__ agg, const float* __restrict__ h,
                           const float* __restrict__ dinv, const float* __restrict__ b) {
    int t = blockIdx.x * 256 + threadIdx.x;  // kN*kH
    int n = t >> 5, c = t & 31;
    agg[t] += h[t] * dinv[n] * dinv[n] + b[c];
}

// graphnorm over nodes (per channel), then relu. One block per channel.
__global__ void k_graphnorm(const float* __restrict__ x, float* __restrict__ out,
                            const float* __restrict__ g, const float* __restrict__ b,
                            const float* __restrict__ a, int M) {
    int c = blockIdx.x, t = threadIdx.x;
    float s = 0.f, ss = 0.f;
    for (int m = t; m < M; m += 256) { float v = x[m * kH + c]; s += v; ss += v * v; }
    __shared__ float rs[256], rss[256];
    rs[t] = s; rss[t] = ss;
    __syncthreads();
    for (int o = 128; o > 0; o >>= 1) {
        if (t < o) { rs[t] += rs[t + o]; rss[t] += rss[t + o]; }
        __syncthreads();
    }
    __shared__ float scale, shift;
    if (t == 0) {
        float mu  = rs[0] / (float)M;
        float ac  = a[c];
        float var = rss[0] / (float)M - 2.f * ac * mu * mu + ac * ac * mu * mu;
        float sc  = g[c] * rsqrtf(var + kEPS);
        scale = sc;
        shift = b[c] - sc * ac * mu;
    }
    __syncthreads();
    for (int m = t; m < M; m += 256) {
        float v = scale * x[m * kH + c] + shift;
        out[m * kH + c] = v > 0.f ? v : 0.f;
    }
}

// ---------------- x1 / x2^T generation (bf16, channel-major) — R3-proven unfused form ----------------
// X[cc][o][in] = relu( W·(xn[o] ⊙ xn[in]) + adjX[o][in]·W_e + b ), bf16.
// For X1: o=i, in=j, adjX=adj.  For X2^T: o=j, in=k, adjX=adj^T (pair product is symmetric).

template<int CW>
__global__ __launch_bounds__(256) void k_genx(
        const float* __restrict__ xn, const unsigned char* __restrict__ adjX,
        const float* __restrict__ w, const float* __restrict__ b,
        __hip_bfloat16* __restrict__ X, int c0) {
    __shared__ float Ws[33 * CW], bs[CW], xo[kH];
    __shared__ float xis[256][kH + 1];
    int o = blockIdx.y, i0 = blockIdx.x * 256, t = threadIdx.x;
    for (int u = t; u < 33 * CW; u += 256) {
        int d = u / CW, cc = u % CW;
        Ws[u] = w[d * kH + c0 + cc];
    }
    if (t < CW) bs[t] = b[c0 + t];
    if (t < kH) xo[t] = xn[o * kH + t];
    for (int u = t; u < 256 * kH; u += 256) {
        xis[u >> 5][u & 31] = xn[(i0 + (u >> 5)) * kH + (u & 31)];
    }
    __syncthreads();
    int in = i0 + t;
    float p[kH];
#pragma unroll
    for (int d = 0; d < kH; d++) p[d] = xo[d] * xis[t][d];
    float e = (float)adjX[o * kN + in];
#pragma unroll
    for (int cc = 0; cc < CW; cc++) {
        float v = bs[cc];
#pragma unroll
        for (int d = 0; d < kH; d++) v = fmaf(p[d], Ws[d * CW + cc], v);
        v = fmaf(e, Ws[32 * CW + cc], v);
        X[(size_t)cc * kNN + (size_t)o * kN + in] = __float2bfloat16(v > 0.f ? v : 0.f);
    }
}

// ---------------- bf16 MFMA batched GEMM: C[c] = A[c] @ B[c], B given transposed ----------------

__device__ __forceinline__ void g2l16(const unsigned short* g, unsigned short* l) {
    __builtin_amdgcn_global_load_lds(
        (const __attribute__((address_space(1))) void*)g,
        (__attribute__((address_space(3))) void*)l, 16, 0, 0);
}

__global__ __launch_bounds__(256) void k_bgemm_bf16(
        const unsigned short* __restrict__ A_, const unsigned short* __restrict__ Bt_,
        float* __restrict__ C_) {
    int c = blockIdx.z;
    const unsigned short* A  = A_  + (size_t)c * kNN;
    const unsigned short* Bt = Bt_ + (size_t)c * kNN;
    float* C = C_ + (size_t)c * kNN;
    int i0 = blockIdx.y * 128, j0 = blockIdx.x * 128;
    __shared__ unsigned short As[128 * 32];
    __shared__ unsigned short Bs[128 * 32];
    int t = threadIdx.x;
    int lane = t & 63, w = t >> 6;
    int wr = (w >> 1) * 64, wc = (w & 1) * 64;
    int l15 = lane & 15, lhi = lane >> 4;  // 0..3
    int srow = t >> 2, skel = (t & 3) * 8;
    f32x4 acc[4][4] = {};
    for (int k0 = 0; k0 < kN; k0 += 32) {
        g2l16(A  + (size_t)(i0 + srow)      * kN + k0 + skel, As + (size_t)t * 8);
        g2l16(A  + (size_t)(i0 + srow + 64) * kN + k0 + skel, As + (size_t)(t + 256) * 8);
        g2l16(Bt + (size_t)(j0 + srow)      * kN + k0 + skel, Bs + (size_t)t * 8);
        g2l16(Bt + (size_t)(j0 + srow + 64) * kN + k0 + skel, Bs + (size_t)(t + 256) * 8);
        asm volatile("s_waitcnt vmcnt(0)" ::: "memory");
        __syncthreads();
        short8 af[4], bf[4];
#pragma unroll
        for (int m = 0; m < 4; m++)
            af[m] = *(const short8*)&As[(wr + m * 16 + l15) * 32 + lhi * 8];
#pragma unroll
        for (int n = 0; n < 4; n++)
            bf[n] = *(const short8*)&Bs[(wc + n * 16 + l15) * 32 + lhi * 8];
#pragma unroll
        for (int m = 0; m < 4; m++)
#pragma unroll
            for (int n = 0; n < 4; n++)
                acc[m][n] = __builtin_amdgcn_mfma_f32_16x16x32_bf16(af[m], bf[n], acc[m][n], 0, 0, 0);
        __syncthreads();
    }
#pragma unroll
    for (int m = 0; m < 4; m++) {
        int row = i0 + wr + m * 16 + lhi * 4;
#pragma unroll
        for (int n = 0; n < 4; n++) {
            int col = j0 + wc + n * 16 + l15;
#pragma unroll
            for (int r = 0; r < 4; r++)
                C[(size_t)(row + r) * kN + col] = acc[m][n][r];
        }
    }
}

// ---------------- gn3 statistics ----------------
// 1024 blocks = one i-row each, 4 k-tiles of 256. P-tile staged to LDS with
// coalesced float4 loads; per-block partials to spart[block][64] (deterministic).

__global__ __launch_bounds__(256) void k_stats(
        const float* __restrict__ xn, const unsigned char* __restrict__ adj,
        const float* __restrict__ prod, const float* __restrict__ w3,
        const float* __restrict__ b3, float* __restrict__ spart) {
    __shared__ float Pt[kH][256];        // 32 KB staged P-tile
    __shared__ float W3T[kH * 68];
    __shared__ float b3s[kH], xi[kH], lsum[kH], lssq[kH];
    int t = threadIdx.x;
    for (int u = t; u < 65 * kH; u += 256) {
        int d = u >> 5, c = u & 31;                 // w3 row-major [65][32]
        int slot = d < 33 ? d : d + 3;
        W3T[c * 68 + slot] = w3[u];
    }
    int i = blockIdx.x;
    if (t < kH) { b3s[t] = b3[t]; lsum[t] = 0.f; lssq[t] = 0.f; }
    else if (t < 2 * kH) xi[t - kH] = xn[i * kH + (t - kH)];
    float s[kH] = {}, q2[kH] = {};
    for (int kt = 0; kt < 4; kt++) {
        int k0 = kt * 256;
        __syncthreads();   // protect Pt reuse (iter0: covers W3T/xi staging too)
        for (int u = t; u < kH * 64; u += 256) {    // 2048 float4 slots
            int d = u >> 6, c4 = (u & 63) << 2;
            *(float4*)&Pt[d][c4] =
                *(const float4*)&prod[(size_t)d * kNN + (size_t)i * kN + k0 + c4];
        }
        __syncthreads();
        int k = k0 + t;
        float p[kH];
#pragma unroll
        for (int q = 0; q < 8; q++) {
            float4 v = *(const float4*)&xn[k * kH + 4 * q];
            p[4 * q + 0] = xi[4 * q + 0] * v.x;
            p[4 * q + 1] = xi[4 * q + 1] * v.y;
            p[4 * q + 2] = xi[4 * q + 2] * v.z;
            p[4 * q + 3] = xi[4 * q + 3] * v.w;
        }
        float e = (float)adj[i * kN + k];
        float pr[kH];
#pragma unroll
        for (int d = 0; d < kH; d++) pr[d] = Pt[d][t];   // 2-way bank alias: free
#pragma unroll 4
        for (int c = 0; c < kH; c++) {
            const float* wc = &W3T[c * 68];
            float v = b3s[c];
#pragma unroll
            for (int q = 0; q < 8; q++) {
                float4 w4 = *(const float4*)(wc + 4 * q);
                v = fmaf(p[4 * q + 0], w4.x, v); v = fmaf(p[4 * q + 1], w4.y, v);
                v = fmaf(p[4 * q + 2], w4.z, v); v = fmaf(p[4 * q + 3], w4.w, v);
            }
            v = fmaf(e, wc[32], v);
#pragma unroll
            for (int q = 0; q < 8; q++) {
                float4 w4 = *(const float4*)(wc + 36 + 4 * q);
                v = fmaf(pr[4 * q + 0], w4.x, v); v = fmaf(pr[4 * q + 1], w4.y, v);
                v = fmaf(pr[4 * q + 2], w4.z, v); v = fmaf(pr[4 * q + 3], w4.w, v);
            }
            s[c] += v;
            q2[c] = fmaf(v, v, q2[c]);
        }
    }
    // 64-lane butterfly per channel, LDS partials, one global write per block
#pragma unroll 4
    for (int c = 0; c < kH; c++) {
        float a = s[c], b = q2[c];
#pragma unroll
        for (int o = 32; o > 0; o >>= 1) { a += __shfl_xor(a, o); b += __shfl_xor(b, o); }
        if ((t & 63) == 0) { atomicAdd(&lsum[c], a); atomicAdd(&lssq[c], b); }
    }
    __syncthreads();
    if (t < kH)          spart[(size_t)i * 64 + t]             = lsum[t];
    else if (t < 2 * kH) spart[(size_t)i * 64 + 32 + (t - kH)] = lssq[t - kH];
}

// parallel reduce spart[1024][64] -> stats[64]
__global__ __launch_bounds__(256) void k_reduce(const float* __restrict__ spart,
                                                float* __restrict__ stats) {
    int slot = blockIdx.x;   // 64 blocks
    int t = threadIdx.x;
    float acc = 0.f;
    for (int r = t; r < kStatsBlocks; r += 256) acc += spart[(size_t)r * 64 + slot];
    __shared__ float red[256];
    red[t] = acc;
    __syncthreads();
    for (int o = 128; o > 0; o >>= 1) {
        if (t < o) red[t] += red[t + o];
        __syncthreads();
    }
    if (t == 0) stats[slot] = red[0];
}

__global__ void k_finalize(const float* __restrict__ stats, const float* __restrict__ g,
                           const float* __restrict__ b, const float* __restrict__ a,
                           float* __restrict__ ss) {
    int c = threadIdx.x;  // 32 threads
    float M   = (float)((double)kNN);
    float mu  = stats[c] / M;
    float ac  = a[c];
    float var = stats[kH + c] / M - 2.f * ac * mu * mu + ac * ac * mu * mu;
    float sc  = g[c] * rsqrtf(var + kEPS);
    ss[c]      = sc;
    ss[kH + c] = b[c] - sc * ac * mu;
}

// ---------------- final: recompute y at (i,k) and (k,i), symmetrize, project ----------------

__global__ __launch_bounds__(256) void k_out(
        const int* __restrict__ pos, const float* __restrict__ xn,
        const unsigned char* __restrict__ adj, const float* __restrict__ prod,
        const float* __restrict__ w3, const float* __restrict__ b3,
        const float* __restrict__ ss, const float* __restrict__ wdir,
        const float* __restrict__ bdir, float* __restrict__ out) {
    __shared__ float W3s[65 * kH], b3s[kH], scs[kH], shs[kH], wd[kH];
    int t = threadIdx.x;
    for (int u = t; u < 65 * kH; u += 256) W3s[u] = w3[u];
    if (t < kH) { b3s[t] = b3[t]; scs[t] = ss[t]; shs[t] = ss[kH + t]; wd[t] = wdir[t]; }
    __syncthreads();
    int q = blockIdx.x * 256 + t;
    int i = pos[2 * q], k = pos[2 * q + 1];
    float p[kH], pr1[kH], pr2[kH];
#pragma unroll
    for (int d = 0; d < kH; d++) p[d] = xn[i * kH + d] * xn[k * kH + d];
#pragma unroll
    for (int d = 0; d < kH; d++) {
        pr1[d] = prod[(size_t)d * kNN + (size_t)i * kN + k];
        pr2[d] = prod[(size_t)d * kNN + (size_t)k * kN + i];
    }
    float e1 = (float)adj[i * kN + k], e2 = (float)adj[k * kN + i];
    float acc = bdir[0];
    for (int c = 0; c < kH; c++) {
        float y1 = b3s[c], y2 = b3s[c];
#pragma unroll
        for (int d = 0; d < kH; d++) {
            float w = W3s[d * kH + c];
            y1 = fmaf(p[d], w, y1); y2 = fmaf(p[d], w, y2);
        }
        y1 = fmaf(e1, W3s[32 * kH + c], y1);
        y2 = fmaf(e2, W3s[32 * kH + c], y2);
#pragma unroll
        for (int d = 0; d < kH; d++) {
            float w = W3s[(33 + d) * kH + c];
            y1 = fmaf(pr1[d], w, y1); y2 = fmaf(pr2[d], w, y2);
        }
        float z1 = scs[c] * y1 + shs[c]; z1 = z1 > 0.f ? z1 : 0.f;
        float z2 = scs[c] * y2 + shs[c]; z2 = z2 > 0.f ? z2 : 0.f;
        acc = fmaf(z1 * z2, wd[c], acc);
    }
    out[q] = acc;
}

// ---------------- launch ----------------

extern "C" void kernel_launch(void* const* d_in, const int* in_sizes, int n_in,
                              void* d_out, int out_size, void* d_ws, size_t ws_size,
                              hipStream_t stream) {
    const int*   x_ids = (const int*)d_in[0];
    const int*   ei    = (const int*)d_in[1];
    const int*   pos   = (const int*)d_in[2];
    const float* emb   = (const float*)d_in[3];
    const float* gw0   = (const float*)d_in[4];
    const float* gb0   = (const float*)d_in[5];
    const float* g0g   = (const float*)d_in[6];
    const float* g0b   = (const float*)d_in[7];
    const float* g0a   = (const float*)d_in[8];
    const float* gw1   = (const float*)d_in[9];
    const float* gb1   = (const float*)d_in[10];
    const float* g1g   = (const float*)d_in[11];
    const float* g1b   = (const float*)d_in[12];
    const float* g1a   = (const float*)d_in[13];
    const float* wm1   = (const float*)d_in[14];
    const float* bm1   = (const float*)d_in[15];
    const float* wm2   = (const float*)d_in[16];
    const float* bm2   = (const float*)d_in[17];
    const float* wm3   = (const float*)d_in[18];
    const float* bm3   = (const float*)d_in[19];
    const float* g3g   = (const float*)d_in[20];
    const float* g3b   = (const float*)d_in[21];
    const float* g3a   = (const float*)d_in[22];
    const float* wdir  = (const float*)d_in[23];
    const float* bdir  = (const float*)d_in[24];
    float* out = (float*)d_out;

    // workspace layout — fixed CW=8, total demand ~162.9 MB (R3-proven fit)
    const size_t fixedF = (size_t)kH * kNN;                       // prod floats
    float* prod = (float*)d_ws;                                   // 128 MB
    unsigned short* X1c = (unsigned short*)(prod + fixedF);       // 16 MB bf16
    unsigned short* X2c = X1c + (size_t)kCW * kNN;                // 16 MB bf16 (transposed)
    unsigned char* adj  = (unsigned char*)(X2c + (size_t)kCW * kNN);  // 1 MB
    unsigned char* adjT = adj + kNN;                                   // 1 MB
    float* deg   = (float*)(adjT + kNN);
    float* dinv  = deg + kN;
    float* x0    = dinv + kN;
    float* h     = x0 + kN * kH;
    float* agg   = h + kN * kH;
    float* xa    = agg + kN * kH;
    float* xb    = xa + kN * kH;
    float* spart = xb + kN * kH;                 // 1024*64 floats (256 KB)
    float* stats = spart + (size_t)kStatsBlocks * 64;
    float* ss    = stats + 2 * kH;

    hipMemsetAsync(deg, 0, kN * sizeof(float), stream);
    hipMemsetAsync(adj, 0, 2 * kNN, stream);   // adj + adjT contiguous
    hipMemsetAsync(agg, 0, kN * kH * sizeof(float), stream);

    k_edge<<<(kE + 255) / 256, 256, 0, stream>>>(ei, deg, adj, adjT);
    k_dinv<<<4, 256, 0, stream>>>(deg, dinv);
    k_embed<<<kN * kH / 256, 256, 0, stream>>>(x_ids, emb, x0);

    // GCN layer 0
    k_node_mm<<<kN * kH / 256, 256, 0, stream>>>(x0, gw0, h);
    k_scatter<<<kE * kH / 256, 256, 0, stream>>>(ei, h, dinv, agg);
    k_gcn_post<<<kN * kH / 256, 256, 0, stream>>>(agg, h, dinv, gb0);
    k_graphnorm<<<kH, 256, 0, stream>>>(agg, xa, g0g, g0b, g0a, kN);

    // GCN layer 1
    hipMemsetAsync(agg, 0, kN * kH * sizeof(float), stream);
    k_node_mm<<<kN * kH / 256, 256, 0, stream>>>(xa, gw1, h);
    k_scatter<<<kE * kH / 256, 256, 0, stream>>>(ei, h, dinv, agg);
    k_gcn_post<<<kN * kH / 256, 256, 0, stream>>>(agg, h, dinv, gb1);
    k_graphnorm<<<kH, 256, 0, stream>>>(agg, xb, g1g, g1b, g1a, kN);

    // pairwise bf16 features (unfused, R3-proven) + batched MFMA GEMMs, CW=8
    for (int c0 = 0; c0 < kH; c0 += kCW) {
        k_genx<kCW><<<dim3(4, kN), 256, 0, stream>>>(xb, adj,  wm1, bm1,
                                                     (__hip_bfloat16*)X1c, c0);
        k_genx<kCW><<<dim3(4, kN), 256, 0, stream>>>(xb, adjT, wm2, bm2,
                                                     (__hip_bfloat16*)X2c, c0);
        k_bgemm_bf16<<<dim3(8, 8, kCW), 256, 0, stream>>>(X1c, X2c, prod + (size_t)c0 * kNN);
    }

    // gn3 stats: LDS-staged P-tiles, deterministic partials + parallel reduce
    k_stats<<<kStatsBlocks, 256, 0, stream>>>(xb, adj, prod, wm3, bm3, spart);
    k_reduce<<<64, 256, 0, stream>>>(spart, stats);
    k_finalize<<<1, 32, 0, stream>>>(stats, g3g, g3b, g3a, ss);

    // final gather + symmetric product + projection
    k_out<<<kQ / 256, 256, 0, stream>>>(pos, xb, adj, prod, wm3, bm3, ss, wdir, bdir, out);
}

// Round 8
// 573.862 us; speedup vs baseline: 1.6555x; 1.1584x over previous
//
#include <hip/hip_runtime.h>
#include <hip/hip_bf16.h>
#include <cstddef>

constexpr int   kN  = 1024;
constexpr int   kE  = 16384;
constexpr int   kQ  = 8192;
constexpr int   kH  = 32;
constexpr size_t kNN = (size_t)kN * kN;
constexpr float kEPS = 1e-5f;
constexpr int   kCW = 8;              // channel chunk width, pinned (R3-proven)
constexpr int   kStatsBlocks = kN;    // one i-row per block

using short8 = __attribute__((ext_vector_type(8))) short;
using f32x4  = __attribute__((ext_vector_type(4))) float;

__device__ __forceinline__ unsigned short f2bf(float f) {
    __hip_bfloat16 h = __float2bfloat16(f);
    return *reinterpret_cast<unsigned short*>(&h);
}

// ---------------- small graph kernels ----------------

__global__ void k_edge(const int* __restrict__ ei, float* __restrict__ deg,
                       unsigned char* __restrict__ adj, unsigned char* __restrict__ adjT) {
    int e = blockIdx.x * 256 + threadIdx.x;
    if (e < kE) {
        int s = ei[e], d = ei[kE + e];
        atomicAdd(&deg[d], 1.0f);
        adj [s * kN + d] = 1;   // eim[s][d]
        adjT[d * kN + s] = 1;   // eim^T
    }
}

__global__ void k_dinv(const float* __restrict__ deg, float* __restrict__ dinv) {
    int n = blockIdx.x * 256 + threadIdx.x;
    if (n < kN) dinv[n] = rsqrtf(deg[n] + 1.0f);
}

__global__ void k_embed(const int* __restrict__ xids, const float* __restrict__ emb,
                        float* __restrict__ x0) {
    int t = blockIdx.x * 256 + threadIdx.x;  // kN*kH threads
    int n = t >> 5, c = t & 31;
    x0[t] = emb[xids[n] * kH + c];
}

// h = x @ W   (kN x 32) @ (32 x 32)
__global__ void k_node_mm(const float* __restrict__ x, const float* __restrict__ W,
                          float* __restrict__ h) {
    __shared__ float Ws[kH * kH];
    int t = threadIdx.x;
    for (int u = t; u < kH * kH; u += 256) Ws[u] = W[u];
    __syncthreads();
    int g = blockIdx.x * 256 + t;
    int n = g >> 5, c = g & 31;
    float acc = 0.f;
#pragma unroll
    for (int d = 0; d < kH; d++) acc = fmaf(x[n * kH + d], Ws[d * kH + c], acc);
    h[g] = acc;
}

__global__ void k_scatter(const int* __restrict__ ei, const float* __restrict__ h,
                          const float* __restrict__ dinv, float* __restrict__ agg) {
    int t = blockIdx.x * 256 + threadIdx.x;  // kE*kH threads
    int e = t >> 5, c = t & 31;
    int s = ei[e], d = ei[kE + e];
    atomicAdd(&agg[d * kH + c], h[s * kH + c] * dinv[s] * dinv[d]);
}

__global__ void k_gcn_post(float* __restrict__ agg, const float* __restrict__ h,
                           const float* __restrict__ dinv, const float* __restrict__ b) {
    int t = blockIdx.x * 256 + threadIdx.x;  // kN*kH
    int n = t >> 5, c = t & 31;
    agg[t] += h[t] * dinv[n] * dinv[n] + b[c];
}

// graphnorm over nodes (per channel), then relu. One block per channel.
__global__ void k_graphnorm(const float* __restrict__ x, float* __restrict__ out,
                            const float* __restrict__ g, const float* __restrict__ b,
                            const float* __restrict__ a, int M) {
    int c = blockIdx.x, t = threadIdx.x;
    float s = 0.f, ss = 0.f;
    for (int m = t; m < M; m += 256) { float v = x[m * kH + c]; s += v; ss += v * v; }
    __shared__ float rs[256], rss[256];
    rs[t] = s; rss[t] = ss;
    __syncthreads();
    for (int o = 128; o > 0; o >>= 1) {
        if (t < o) { rs[t] += rs[t + o]; rss[t] += rss[t + o]; }
        __syncthreads();
    }
    __shared__ float scale, shift;
    if (t == 0) {
        float mu  = rs[0] / (float)M;
        float ac  = a[c];
        float var = rss[0] / (float)M - 2.f * ac * mu * mu + ac * ac * mu * mu;
        float sc  = g[c] * rsqrtf(var + kEPS);
        scale = sc;
        shift = b[c] - sc * ac * mu;
    }
    __syncthreads();
    for (int m = t; m < M; m += 256) {
        float v = scale * x[m * kH + c] + shift;
        out[m * kH + c] = v > 0.f ? v : 0.f;
    }
}

// ---------------- x1 / x2^T generation (bf16, channel-major) — R3-proven unfused form ----------------

template<int CW>
__global__ __launch_bounds__(256) void k_genx(
        const float* __restrict__ xn, const unsigned char* __restrict__ adjX,
        const float* __restrict__ w, const float* __restrict__ b,
        __hip_bfloat16* __restrict__ X, int c0) {
    __shared__ float Ws[33 * CW], bs[CW], xo[kH];
    __shared__ float xis[256][kH + 1];
    int o = blockIdx.y, i0 = blockIdx.x * 256, t = threadIdx.x;
    for (int u = t; u < 33 * CW; u += 256) {
        int d = u / CW, cc = u % CW;
        Ws[u] = w[d * kH + c0 + cc];
    }
    if (t < CW) bs[t] = b[c0 + t];
    if (t < kH) xo[t] = xn[o * kH + t];
    for (int u = t; u < 256 * kH; u += 256) {
        xis[u >> 5][u & 31] = xn[(i0 + (u >> 5)) * kH + (u & 31)];
    }
    __syncthreads();
    int in = i0 + t;
    float p[kH];
#pragma unroll
    for (int d = 0; d < kH; d++) p[d] = xo[d] * xis[t][d];
    float e = (float)adjX[o * kN + in];
#pragma unroll
    for (int cc = 0; cc < CW; cc++) {
        float v = bs[cc];
#pragma unroll
        for (int d = 0; d < kH; d++) v = fmaf(p[d], Ws[d * CW + cc], v);
        v = fmaf(e, Ws[32 * CW + cc], v);
        X[(size_t)cc * kNN + (size_t)o * kN + in] = __float2bfloat16(v > 0.f ? v : 0.f);
    }
}

// ---------------- bf16 MFMA batched GEMM: C[c] = A[c] @ B[c], B given transposed ----------------

__device__ __forceinline__ void g2l16(const unsigned short* g, unsigned short* l) {
    __builtin_amdgcn_global_load_lds(
        (const __attribute__((address_space(1))) void*)g,
        (__attribute__((address_space(3))) void*)l, 16, 0, 0);
}

__global__ __launch_bounds__(256) void k_bgemm_bf16(
        const unsigned short* __restrict__ A_, const unsigned short* __restrict__ Bt_,
        float* __restrict__ C_) {
    int c = blockIdx.z;
    const unsigned short* A  = A_  + (size_t)c * kNN;
    const unsigned short* Bt = Bt_ + (size_t)c * kNN;
    float* C = C_ + (size_t)c * kNN;
    int i0 = blockIdx.y * 128, j0 = blockIdx.x * 128;
    __shared__ unsigned short As[128 * 32];
    __shared__ unsigned short Bs[128 * 32];
    int t = threadIdx.x;
    int lane = t & 63, w = t >> 6;
    int wr = (w >> 1) * 64, wc = (w & 1) * 64;
    int l15 = lane & 15, lhi = lane >> 4;  // 0..3
    int srow = t >> 2, skel = (t & 3) * 8;
    f32x4 acc[4][4] = {};
    for (int k0 = 0; k0 < kN; k0 += 32) {
        g2l16(A  + (size_t)(i0 + srow)      * kN + k0 + skel, As + (size_t)t * 8);
        g2l16(A  + (size_t)(i0 + srow + 64) * kN + k0 + skel, As + (size_t)(t + 256) * 8);
        g2l16(Bt + (size_t)(j0 + srow)      * kN + k0 + skel, Bs + (size_t)t * 8);
        g2l16(Bt + (size_t)(j0 + srow + 64) * kN + k0 + skel, Bs + (size_t)(t + 256) * 8);
        asm volatile("s_waitcnt vmcnt(0)" ::: "memory");
        __syncthreads();
        short8 af[4], bf[4];
#pragma unroll
        for (int m = 0; m < 4; m++)
            af[m] = *(const short8*)&As[(wr + m * 16 + l15) * 32 + lhi * 8];
#pragma unroll
        for (int n = 0; n < 4; n++)
            bf[n] = *(const short8*)&Bs[(wc + n * 16 + l15) * 32 + lhi * 8];
#pragma unroll
        for (int m = 0; m < 4; m++)
#pragma unroll
            for (int n = 0; n < 4; n++)
                acc[m][n] = __builtin_amdgcn_mfma_f32_16x16x32_bf16(af[m], bf[n], acc[m][n], 0, 0, 0);
        __syncthreads();
    }
#pragma unroll
    for (int m = 0; m < 4; m++) {
        int row = i0 + wr + m * 16 + lhi * 4;
#pragma unroll
        for (int n = 0; n < 4; n++) {
            int col = j0 + wc + n * 16 + l15;
#pragma unroll
            for (int r = 0; r < 4; r++)
                C[(size_t)(row + r) * kN + col] = acc[m][n][r];
        }
    }
}

// ---------------- gn3 statistics via MFMA ----------------
// y[pair][c] = feat[pair][:] @ W3aug, feat K-layout (Kpad=104, logical 96):
//   [0..31]=p, [32]=e, [33]=0, [34..65]=pr, [66]=1 (bias), [67..95]=0.
// Per i-row block: 8 tiles of 128 pairs; feat staged bf16 in LDS; y stays in
// C-fragments; sum/sumsq accumulated per-lane (channel = ct*16 + (lane&15)).

__global__ __launch_bounds__(256) void k_stats_mfma(
        const float* __restrict__ xn, const unsigned char* __restrict__ adj,
        const float* __restrict__ prod, const float* __restrict__ w3,
        const float* __restrict__ b3, float* __restrict__ spart) {
    __shared__ unsigned short As[128 * 104];   // 26.6 KB feat tile
    __shared__ unsigned short Bs[32 * 104];    // 6.7 KB W3aug^T [c][k]
    __shared__ float xi[kH], lsum[kH], lssq[kH];
    int t = threadIdx.x;
    int i = blockIdx.x;
    int lane = t & 63, w = t >> 6;
    int l15 = lane & 15, lhi = lane >> 4;

    // init: zero As (pads), set 1-column, build W3aug^T, xi, lsum/lssq
    for (int u = t; u < 128 * 104 / 8; u += 256)
        *(short8*)&As[u * 8] = short8{0, 0, 0, 0, 0, 0, 0, 0};
    {   // W3aug^T: c = t&31, s-range (t>>5)*13..+13
        int c = t & 31, s0 = (t >> 5) * 13;
        for (int s = s0; s < s0 + 13; s++) {
            float v = 0.f;
            if (s <= 32)                 v = w3[s * kH + c];
            else if (s >= 34 && s <= 65) v = w3[(s - 1) * kH + c];
            else if (s == 66)            v = b3[c];
            Bs[c * 104 + s] = f2bf(v);
        }
    }
    if (t < kH) { xi[t] = xn[i * kH + t]; lsum[t] = 0.f; lssq[t] = 0.f; }
    __syncthreads();
    if (t < 128) As[t * 104 + 66] = f2bf(1.0f);   // bias column (persists)

    float s2[2] = {0.f, 0.f}, q22[2] = {0.f, 0.f};
    int wrow = w * 32;

    for (int kt = 0; kt < 8; kt++) {
        int kbase = kt * 128;
        // ---- stage p (slots 0..31): thread -> (row r = t>>1, half = t&1)
        {
            int r = t >> 1, half = t & 1;
            int k = kbase + r;
            const float* xr = &xn[k * kH + half * 16];
            float4 v0 = *(const float4*)&xr[0];
            float4 v1 = *(const float4*)&xr[4];
            float4 v2 = *(const float4*)&xr[8];
            float4 v3 = *(const float4*)&xr[12];
            const float* xih = &xi[half * 16];
            short8 o0, o1;
            o0[0] = f2bf(xih[0] * v0.x);  o0[1] = f2bf(xih[1] * v0.y);
            o0[2] = f2bf(xih[2] * v0.z);  o0[3] = f2bf(xih[3] * v0.w);
            o0[4] = f2bf(xih[4] * v1.x);  o0[5] = f2bf(xih[5] * v1.y);
            o0[6] = f2bf(xih[6] * v1.z);  o0[7] = f2bf(xih[7] * v1.w);
            o1[0] = f2bf(xih[8] * v2.x);  o1[1] = f2bf(xih[9] * v2.y);
            o1[2] = f2bf(xih[10] * v2.z); o1[3] = f2bf(xih[11] * v2.w);
            o1[4] = f2bf(xih[12] * v3.x); o1[5] = f2bf(xih[13] * v3.y);
            o1[6] = f2bf(xih[14] * v3.z); o1[7] = f2bf(xih[15] * v3.w);
            *(short8*)&As[r * 104 + half * 16]     = o0;
            *(short8*)&As[r * 104 + half * 16 + 8] = o1;
        }
        // ---- stage e (slot 32)
        if (t < 128) As[t * 104 + 32] = f2bf((float)adj[i * kN + kbase + t]);
        // ---- stage pr (slots 34..65): thread -> (kq = t&15, dp = t>>4)
        {
            int kq = t & 15, dp = t >> 4, d2 = dp * 2;
            const float* p0 = &prod[(size_t)d2 * kNN + (size_t)i * kN + kbase + kq * 8];
            const float* p1 = p0 + kNN;
            float4 a0 = *(const float4*)&p0[0];
            float4 a1 = *(const float4*)&p0[4];
            float4 b0 = *(const float4*)&p1[0];
            float4 b1 = *(const float4*)&p1[4];
            float r0[8] = {a0.x, a0.y, a0.z, a0.w, a1.x, a1.y, a1.z, a1.w};
            float r1[8] = {b0.x, b0.y, b0.z, b0.w, b1.x, b1.y, b1.z, b1.w};
            unsigned int* As32 = (unsigned int*)As;
#pragma unroll
            for (int j = 0; j < 8; j++) {
                int jr = (j + kq) & 7;                  // rotate to spread banks
                int kl = kq * 8 + jr;
                unsigned int val = (unsigned int)f2bf(r0[jr]) |
                                   ((unsigned int)f2bf(r1[jr]) << 16);
                As32[kl * 52 + 17 + dp] = val;          // slots 34+d2, 35+d2
            }
        }
        __syncthreads();
        // ---- MFMA: rows wrow..wrow+31 (2 rt), channels 0..31 (2 ct), K=96 (3 ks)
        f32x4 acc[2][2] = {};
#pragma unroll
        for (int ks = 0; ks < 3; ks++) {
            short8 af0 = *(const short8*)&As[(wrow + l15) * 104 + ks * 32 + lhi * 8];
            short8 af1 = *(const short8*)&As[(wrow + 16 + l15) * 104 + ks * 32 + lhi * 8];
            short8 bf0 = *(const short8*)&Bs[l15 * 104 + ks * 32 + lhi * 8];
            short8 bf1 = *(const short8*)&Bs[(16 + l15) * 104 + ks * 32 + lhi * 8];
            acc[0][0] = __builtin_amdgcn_mfma_f32_16x16x32_bf16(af0, bf0, acc[0][0], 0, 0, 0);
            acc[0][1] = __builtin_amdgcn_mfma_f32_16x16x32_bf16(af0, bf1, acc[0][1], 0, 0, 0);
            acc[1][0] = __builtin_amdgcn_mfma_f32_16x16x32_bf16(af1, bf0, acc[1][0], 0, 0, 0);
            acc[1][1] = __builtin_amdgcn_mfma_f32_16x16x32_bf16(af1, bf1, acc[1][1], 0, 0, 0);
        }
#pragma unroll
        for (int ct = 0; ct < 2; ct++)
#pragma unroll
            for (int rt = 0; rt < 2; rt++)
#pragma unroll
                for (int r = 0; r < 4; r++) {
                    float y = acc[rt][ct][r];
                    s2[ct] += y;
                    q22[ct] = fmaf(y, y, q22[ct]);
                }
        __syncthreads();
    }
    // reduce across lhi groups (lanes sharing l15), then LDS, then spart
#pragma unroll
    for (int ct = 0; ct < 2; ct++) {
        s2[ct]  += __shfl_xor(s2[ct], 16);  s2[ct]  += __shfl_xor(s2[ct], 32);
        q22[ct] += __shfl_xor(q22[ct], 16); q22[ct] += __shfl_xor(q22[ct], 32);
    }
    if (lane < 16) {
#pragma unroll
        for (int ct = 0; ct < 2; ct++) {
            atomicAdd(&lsum[ct * 16 + l15], s2[ct]);
            atomicAdd(&lssq[ct * 16 + l15], q22[ct]);
        }
    }
    __syncthreads();
    if (t < kH)          spart[(size_t)i * 64 + t]             = lsum[t];
    else if (t < 2 * kH) spart[(size_t)i * 64 + 32 + (t - kH)] = lssq[t - kH];
}

// parallel reduce spart[1024][64] -> stats[64]
__global__ __launch_bounds__(256) void k_reduce(const float* __restrict__ spart,
                                                float* __restrict__ stats) {
    int slot = blockIdx.x;   // 64 blocks
    int t = threadIdx.x;
    float acc = 0.f;
    for (int r = t; r < kStatsBlocks; r += 256) acc += spart[(size_t)r * 64 + slot];
    __shared__ float red[256];
    red[t] = acc;
    __syncthreads();
    for (int o = 128; o > 0; o >>= 1) {
        if (t < o) red[t] += red[t + o];
        __syncthreads();
    }
    if (t == 0) stats[slot] = red[0];
}

__global__ void k_finalize(const float* __restrict__ stats, const float* __restrict__ g,
                           const float* __restrict__ b, const float* __restrict__ a,
                           float* __restrict__ ss) {
    int c = threadIdx.x;  // 32 threads
    float M   = (float)((double)kNN);
    float mu  = stats[c] / M;
    float ac  = a[c];
    float var = stats[kH + c] / M - 2.f * ac * mu * mu + ac * ac * mu * mu;
    float sc  = g[c] * rsqrtf(var + kEPS);
    ss[c]      = sc;
    ss[kH + c] = b[c] - sc * ac * mu;
}

// ---------------- final: recompute y at (i,k) and (k,i), symmetrize, project ----------------

__global__ __launch_bounds__(256) void k_out(
        const int* __restrict__ pos, const float* __restrict__ xn,
        const unsigned char* __restrict__ adj, const float* __restrict__ prod,
        const float* __restrict__ w3, const float* __restrict__ b3,
        const float* __restrict__ ss, const float* __restrict__ wdir,
        const float* __restrict__ bdir, float* __restrict__ out) {
    __shared__ float W3s[65 * kH], b3s[kH], scs[kH], shs[kH], wd[kH];
    int t = threadIdx.x;
    for (int u = t; u < 65 * kH; u += 256) W3s[u] = w3[u];
    if (t < kH) { b3s[t] = b3[t]; scs[t] = ss[t]; shs[t] = ss[kH + t]; wd[t] = wdir[t]; }
    __syncthreads();
    int q = blockIdx.x * 256 + t;
    int i = pos[2 * q], k = pos[2 * q + 1];
    float p[kH], pr1[kH], pr2[kH];
#pragma unroll
    for (int d = 0; d < kH; d++) p[d] = xn[i * kH + d] * xn[k * kH + d];
#pragma unroll
    for (int d = 0; d < kH; d++) {
        pr1[d] = prod[(size_t)d * kNN + (size_t)i * kN + k];
        pr2[d] = prod[(size_t)d * kNN + (size_t)k * kN + i];
    }
    float e1 = (float)adj[i * kN + k], e2 = (float)adj[k * kN + i];
    float acc = bdir[0];
    for (int c = 0; c < kH; c++) {
        float y1 = b3s[c], y2 = b3s[c];
#pragma unroll
        for (int d = 0; d < kH; d++) {
            float w = W3s[d * kH + c];
            y1 = fmaf(p[d], w, y1); y2 = fmaf(p[d], w, y2);
        }
        y1 = fmaf(e1, W3s[32 * kH + c], y1);
        y2 = fmaf(e2, W3s[32 * kH + c], y2);
#pragma unroll
        for (int d = 0; d < kH; d++) {
            float w = W3s[(33 + d) * kH + c];
            y1 = fmaf(pr1[d], w, y1); y2 = fmaf(pr2[d], w, y2);
        }
        float z1 = scs[c] * y1 + shs[c]; z1 = z1 > 0.f ? z1 : 0.f;
        float z2 = scs[c] * y2 + shs[c]; z2 = z2 > 0.f ? z2 : 0.f;
        acc = fmaf(z1 * z2, wd[c], acc);
    }
    out[q] = acc;
}

// ---------------- launch ----------------

extern "C" void kernel_launch(void* const* d_in, const int* in_sizes, int n_in,
                              void* d_out, int out_size, void* d_ws, size_t ws_size,
                              hipStream_t stream) {
    const int*   x_ids = (const int*)d_in[0];
    const int*   ei    = (const int*)d_in[1];
    const int*   pos   = (const int*)d_in[2];
    const float* emb   = (const float*)d_in[3];
    const float* gw0   = (const float*)d_in[4];
    const float* gb0   = (const float*)d_in[5];
    const float* g0g   = (const float*)d_in[6];
    const float* g0b   = (const float*)d_in[7];
    const float* g0a   = (const float*)d_in[8];
    const float* gw1   = (const float*)d_in[9];
    const float* gb1   = (const float*)d_in[10];
    const float* g1g   = (const float*)d_in[11];
    const float* g1b   = (const float*)d_in[12];
    const float* g1a   = (const float*)d_in[13];
    const float* wm1   = (const float*)d_in[14];
    const float* bm1   = (const float*)d_in[15];
    const float* wm2   = (const float*)d_in[16];
    const float* bm2   = (const float*)d_in[17];
    const float* wm3   = (const float*)d_in[18];
    const float* bm3   = (const float*)d_in[19];
    const float* g3g   = (const float*)d_in[20];
    const float* g3b   = (const float*)d_in[21];
    const float* g3a   = (const float*)d_in[22];
    const float* wdir  = (const float*)d_in[23];
    const float* bdir  = (const float*)d_in[24];
    float* out = (float*)d_out;

    // workspace layout — fixed CW=8, total demand ~162.9 MB (R3-proven fit)
    const size_t fixedF = (size_t)kH * kNN;                       // prod floats
    float* prod = (float*)d_ws;                                   // 128 MB
    unsigned short* X1c = (unsigned short*)(prod + fixedF);       // 16 MB bf16
    unsigned short* X2c = X1c + (size_t)kCW * kNN;                // 16 MB bf16 (transposed)
    unsigned char* adj  = (unsigned char*)(X2c + (size_t)kCW * kNN);  // 1 MB
    unsigned char* adjT = adj + kNN;                                   // 1 MB
    float* deg   = (float*)(adjT + kNN);
    float* dinv  = deg + kN;
    float* x0    = dinv + kN;
    float* h     = x0 + kN * kH;
    float* agg   = h + kN * kH;
    float* xa    = agg + kN * kH;
    float* xb    = xa + kN * kH;
    float* spart = xb + kN * kH;                 // 1024*64 floats (256 KB)
    float* stats = spart + (size_t)kStatsBlocks * 64;
    float* ss    = stats + 2 * kH;

    hipMemsetAsync(deg, 0, kN * sizeof(float), stream);
    hipMemsetAsync(adj, 0, 2 * kNN, stream);   // adj + adjT contiguous
    hipMemsetAsync(agg, 0, kN * kH * sizeof(float), stream);

    k_edge<<<(kE + 255) / 256, 256, 0, stream>>>(ei, deg, adj, adjT);
    k_dinv<<<4, 256, 0, stream>>>(deg, dinv);
    k_embed<<<kN * kH / 256, 256, 0, stream>>>(x_ids, emb, x0);

    // GCN layer 0
    k_node_mm<<<kN * kH / 256, 256, 0, stream>>>(x0, gw0, h);
    k_scatter<<<kE * kH / 256, 256, 0, stream>>>(ei, h, dinv, agg);
    k_gcn_post<<<kN * kH / 256, 256, 0, stream>>>(agg, h, dinv, gb0);
    k_graphnorm<<<kH, 256, 0, stream>>>(agg, xa, g0g, g0b, g0a, kN);

    // GCN layer 1
    hipMemsetAsync(agg, 0, kN * kH * sizeof(float), stream);
    k_node_mm<<<kN * kH / 256, 256, 0, stream>>>(xa, gw1, h);
    k_scatter<<<kE * kH / 256, 256, 0, stream>>>(ei, h, dinv, agg);
    k_gcn_post<<<kN * kH / 256, 256, 0, stream>>>(agg, h, dinv, gb1);
    k_graphnorm<<<kH, 256, 0, stream>>>(agg, xb, g1g, g1b, g1a, kN);

    // pairwise bf16 features (unfused, R3-proven) + batched MFMA GEMMs, CW=8
    for (int c0 = 0; c0 < kH; c0 += kCW) {
        k_genx<kCW><<<dim3(4, kN), 256, 0, stream>>>(xb, adj,  wm1, bm1,
                                                     (__hip_bfloat16*)X1c, c0);
        k_genx<kCW><<<dim3(4, kN), 256, 0, stream>>>(xb, adjT, wm2, bm2,
                                                     (__hip_bfloat16*)X2c, c0);
        k_bgemm_bf16<<<dim3(8, 8, kCW), 256, 0, stream>>>(X1c, X2c, prod + (size_t)c0 * kNN);
    }

    // gn3 stats: MFMA projection, y never materialized
    k_stats_mfma<<<kStatsBlocks, 256, 0, stream>>>(xb, adj, prod, wm3, bm3, spart);
    k_reduce<<<64, 256, 0, stream>>>(spart, stats);
    k_finalize<<<1, 32, 0, stream>>>(stats, g3g, g3b, g3a, ss);

    // final gather + symmetric product + projection
    k_out<<<kQ / 256, 256, 0, stream>>>(pos, xb, adj, prod, wm3, bm3, ss, wdir, bdir, out);
}